// Round 5
// baseline (347.470 us; speedup 1.0000x reference)
//
#include <hip/hip_runtime.h>
#include <utility>

// SSIM3D fused v9: one barrier per plane (kill phase B).
//  - v8 post-mortem: spill gone (4 MB writes, clean 64 VGPR) but 202 us at the
//    same 74 us of VALU time as v4 -> 63% of runtime is barrier/latency stall.
//    Phase B's yp values are each consumed by exactly ONE thread (no reuse!) --
//    cooperative y-staging buys nothing and costs a barrier + 1280 LDS writes
//    per plane.
//  - v9: fold y-conv into phase C (7 zp reads x 5 fields per thread; stride-15
//    addressing = conflict-free), double-buffer zp by plane parity, ONE barrier
//    per plane (33/block vs 66). LDS = 2x5x480 fl = 19.2 KB. Pressure ~76 under
//    the proven cap-128 (launch_bounds(256,4)).
//  - Geometry: ZCH=32, 2016 blocks, XCD swizzle, fused finalize (unchanged).

#define DIMS 192
#define OD   186
#define VOL  (DIMS * DIMS * DIMS)
#define ZCH  32      // z outputs per block (6*32 = 192 >= 186, last tile clipped)
#define NZT  6
#define XCH  27      // x outputs per chunk (7*27 = 189 >= 186, last chunk clipped)
#define NCHX 7
#define NP   (XCH + 6)   // 33 input planes
#define YT   8
#define YIN  14

// LDS: zp[buf][f][k][j]: buf*2400 + f*480 + k*15 + j
//  pitch 15 (odd): A-writes (lane stride 30) <=2-way; C-reads (lane stride 15)
//  hit 32 distinct banks across 32 lanes -> conflict-free.
#define ZP_P    15
#define ZP_F    (ZCH * ZP_P)         // 480
#define ZP_HALF (5 * ZP_F)           // 2400
#define LDS_N   (2 * ZP_HALF)        // 4800 floats = 19.2 KB

#define NBLK   (NZT * 24 * NCHX * 2) // 2016

#define AI __attribute__((always_inline))

__global__ __launch_bounds__(256, 4)
void ssim3d_kernel(const float* __restrict__ X, const float* __restrict__ Y,
                   double* __restrict__ acc_out, unsigned* __restrict__ cnt,
                   float* __restrict__ out) {
    __shared__ float lds[LDS_N];
    __shared__ float wsum[4];
    const int tid = threadIdx.x;

    // 1D Gaussian softmax weights, wave-uniform (SGPR).
    float w[7];
    {
        float s = 0.f;
        #pragma unroll
        for (int t = 0; t < 7; ++t) {
            float d = (float)t - 3.0f;
            w[t] = expf(-d * d / 4.5f);
            s += w[t];
        }
        #pragma unroll
        for (int t = 0; t < 7; ++t)
            w[t] = __uint_as_float(__builtin_amdgcn_readfirstlane(__float_as_uint(w[t] / s)));
    }

    // ---- XCD-chunked bijective swizzle ----
    const int L  = blockIdx.x + NZT * (blockIdx.y + 24 * blockIdx.z);
    const int v  = (L & 7) * (NBLK / 8) + (L >> 3);
    const int cb = v / 144;            // combined (cx, n), 0..13
    const int rem = v - cb * 144;
    const int by  = rem % 24;
    const int bz  = rem / 24;          // 0..5
    const int cx  = cb % NCHX;
    const int n   = cb / NCHX;

    const int z0 = bz * ZCH;
    const int y0 = by * YT;
    const int x0 = cx * XCH;

    const float* Xb = X + (size_t)n * VOL;
    const float* Yb = Y + (size_t)n * VOL;

    // z-phase mapping: thread (zj, zs) -> row zj, z-outputs k = zs*2, zs*2+1
    const int zj = tid >> 4;                 // 0..15 (active < 14)
    const int zs = tid & 15;
    const bool zact = (zj < YIN);
    const int zc = z0 + zs * 2;              // first z-input needed
    const int gy = min(y0 + zj, DIMS - 1);
    const unsigned rowoff = (unsigned)gy * DIMS + (unsigned)zc;
    const bool ztail = (zc + 7 > DIMS - 1);  // only last z-tile, zs >= 13

    // accum mapping: thread owns point (aj, ak); 8 x 32 = 256 exact
    const int aj = tid >> 5;
    const int ak = tid & 31;
    const bool av = (z0 + ak < OD) && (y0 + aj < OD);
    const int xmax = OD + 6 - x0;            // xi < xmax -> output o = x0+xi-6 valid

    float acc[7][5];
    #pragma unroll
    for (int q = 0; q < 7; ++q)
        #pragma unroll
        for (int m = 0; m < 5; ++m) acc[q][m] = 0.f;

    float lsum = 0.f;
    const float c1 = 1e-4f, c2 = 9e-4f;

    float pfx[8], pfy[8];

    auto loadX = [&](int xi) AI {
        if (!zact) return;
        int gx = min(x0 + xi, DIMS - 1);
        const float* p = Xb + (size_t)gx * (DIMS * DIMS);
        if (!ztail) {
            const float* q = p + rowoff;
            #pragma unroll
            for (int t = 0; t < 4; ++t) {
                float2 a = *(const float2*)(q + 2 * t);
                pfx[2 * t] = a.x; pfx[2 * t + 1] = a.y;
            }
        } else {
            unsigned ro = (unsigned)gy * DIMS;
            #pragma unroll
            for (int j = 0; j < 8; ++j)
                pfx[j] = p[ro + (unsigned)min(zc + j, DIMS - 1)];
        }
    };
    auto loadY = [&](int xi) AI {
        if (!zact) return;
        int gx = min(x0 + xi, DIMS - 1);
        const float* p = Yb + (size_t)gx * (DIMS * DIMS);
        if (!ztail) {
            const float* q = p + rowoff;
            #pragma unroll
            for (int t = 0; t < 4; ++t) {
                float2 a = *(const float2*)(q + 2 * t);
                pfy[2 * t] = a.x; pfy[2 * t + 1] = a.y;
            }
        } else {
            unsigned ro = (unsigned)gy * DIMS;
            #pragma unroll
            for (int j = 0; j < 8; ++j)
                pfy[j] = p[ro + (unsigned)min(zc + j, DIMS - 1)];
        }
    };

    auto ssim_pt = [&](float mu1, float mu2, float ex2, float ey2, float exy) AI {
        float mu11 = mu1 * mu1, mu22 = mu2 * mu2, mu12 = mu1 * mu2;
        float num = (2.f * mu12 + c1) * (2.f * (exy - mu12) + c2);
        float den = (mu11 + mu22 + c1) * ((ex2 - mu11) + (ey2 - mu22) + c2);
        lsum += num * __builtin_amdgcn_rcpf(den);
    };

    auto body = [&](int xi, auto ucell) AI {
        constexpr int U = decltype(ucell)::value;   // U == xi % 7
        float* zp = &lds[(xi & 1) * ZP_HALF];       // ping-pong buffer

        // ---- Phase A: z-conv from registers -> zp[buf] ----
        // Race-free vs laggards: they read the OTHER buffer (previous plane);
        // the single barrier below orders this plane's writes before its reads.
        if (zact) {
            #pragma unroll
            for (int o = 0; o < 2; ++o) {
                float a0 = 0.f, a1 = 0.f, a2 = 0.f, a3 = 0.f, a4 = 0.f;
                #pragma unroll
                for (int t = 0; t < 7; ++t) {
                    float xx = pfx[o + t], yy = pfy[o + t], wt = w[t];
                    a0 += wt * xx;
                    a1 += wt * yy;
                    a2 += wt * (xx * xx);
                    a3 += wt * (yy * yy);
                    a4 += wt * (xx * yy);
                }
                int b = (zs * 2 + o) * ZP_P + zj;
                zp[b]            = a0;
                zp[b + ZP_F]     = a1;
                zp[b + 2 * ZP_F] = a2;
                zp[b + 3 * ZP_F] = a3;
                zp[b + 4 * ZP_F] = a4;
            }
        }
        if (xi + 1 < NP) { loadX(xi + 1); loadY(xi + 1); }  // prefetch (WAR after A)
        __syncthreads();

        // ---- Phase C': per-thread y-conv from zp + ring accumulate + SSIM ----
        float yv[5];
        #pragma unroll
        for (int f = 0; f < 5; ++f) {
            const float* src = &zp[f * ZP_F + ak * ZP_P + aj];
            float a = 0.f;
            #pragma unroll
            for (int ty = 0; ty < 7; ++ty) a += w[ty] * src[ty];
            yv[f] = a;
        }
        #pragma unroll
        for (int d = 0; d < 7; ++d) {
            float wq = w[d];
            #pragma unroll
            for (int m = 0; m < 5; ++m)
                acc[(U + 7 - d) % 7][m] += wq * yv[m];   // folds to consts after unroll
        }
        constexpr int sc = (U + 1) % 7;   // slot completing at this plane (o = xi-6)
        if (xi >= 6 && xi < xmax && av)
            ssim_pt(acc[sc][0], acc[sc][1], acc[sc][2], acc[sc][3], acc[sc][4]);
        #pragma unroll
        for (int m = 0; m < 5; ++m) acc[sc][m] = 0.f;
        // No trailing barrier: next Phase A writes the other zp buffer.
    };

    loadX(0); loadY(0);
    #pragma unroll 1
    for (int b = 0; b < 28; b += 7) {
        body(b + 0, std::integral_constant<int, 0>{});
        body(b + 1, std::integral_constant<int, 1>{});
        body(b + 2, std::integral_constant<int, 2>{});
        body(b + 3, std::integral_constant<int, 3>{});
        body(b + 4, std::integral_constant<int, 4>{});
        body(b + 5, std::integral_constant<int, 5>{});
        body(b + 6, std::integral_constant<int, 6>{});
    }
    body(28, std::integral_constant<int, 0>{});
    body(29, std::integral_constant<int, 1>{});
    body(30, std::integral_constant<int, 2>{});
    body(31, std::integral_constant<int, 3>{});
    body(32, std::integral_constant<int, 4>{});

    // ---- block reduction + fused finalize ----
    #pragma unroll
    for (int off = 32; off > 0; off >>= 1) lsum += __shfl_down(lsum, off, 64);
    if ((tid & 63) == 0) wsum[tid >> 6] = lsum;
    __syncthreads();
    if (tid == 0) {
        double bs = (double)(wsum[0] + wsum[1] + wsum[2] + wsum[3]);
        atomicAdd(acc_out, bs);
        __threadfence();
        unsigned prev = atomicAdd(cnt, 1u);
        if (prev == (unsigned)(NBLK - 1)) {
            double tot = atomicAdd(acc_out, 0.0);   // device-scope read of final sum
            out[0] = (float)(tot / 12869712.0);     // 2 * 186^3
        }
    }
}

extern "C" void kernel_launch(void* const* d_in, const int* in_sizes, int n_in,
                              void* d_out, int out_size, void* d_ws, size_t ws_size,
                              hipStream_t stream) {
    (void)in_sizes; (void)n_in; (void)out_size; (void)ws_size;
    const float* x = (const float*)d_in[0];
    const float* y = (const float*)d_in[1];
    double* acc = (double*)d_ws;
    unsigned* cnt = (unsigned*)((char*)d_ws + 8);
    hipMemsetAsync(d_ws, 0, 16, stream);
    dim3 grid(NZT, 24, NCHX * 2);   // z-tiles, y-tiles, x-chunks*batch
    ssim3d_kernel<<<grid, 256, 0, stream>>>(x, y, acc, cnt, (float*)d_out);
}

// Round 6
// 296.673 us; speedup vs baseline: 1.1712x; 1.1712x over previous
//
#include <hip/hip_runtime.h>
#include <utility>

// SSIM3D fused v10: v8 structure + drain-free barriers.
//  - v9 post-mortem: killing phase B raised per-thread LDS reads 5->35/plane
//    (2x LDS-pipe issue) + 35 MB scratch -> 255 us. Reverted to v8 structure.
//  - v10 theory: hipcc emits s_waitcnt vmcnt(0) before every s_barrier
//    (__syncthreads drains ALL memory ops). Our prefetch loads are issued just
//    before each barrier -> their full L2/L3 latency is paid AT the barrier,
//    66x per block, in near-lockstep across all resident blocks. Fix: raw
//    s_barrier + lgkmcnt(0)-only wait (LDS ordering needs lgkm only; loads
//    target registers -> vmcnt waited at first USE, one plane later).
//  - Everything else identical to v8: ZCH=32, LDS 15.4 KB, VGPR 64 (exactly
//    the corner keeping all 2016 blocks resident: 8 blocks/CU, single round),
//    launch_bounds(256,4) cap 128 (spill-cascade-safe), XCD swizzle, fused
//    finalize.

#define DIMS 192
#define OD   186
#define VOL  (DIMS * DIMS * DIMS)
#define ZCH  32      // z outputs per block (6*32 = 192 >= 186, last tile clipped)
#define NZT  6
#define XCH  27      // x outputs per chunk (7*27 = 189 >= 186, last chunk clipped)
#define NCHX 7
#define NP   (XCH + 6)   // 33 input planes
#define YT   8
#define YIN  14

// LDS layouts (floats):
//  zp[f][k][j]: f*480 + k*15 + j   (pitch 15: odd stride -> <=2-way on all access)
//  yp[f][k][j]: f*288 + k*9  + j   (pitch 9)
#define ZP_P   15
#define ZP_F   (ZCH * ZP_P)          // 480
#define YP_P   9
#define YP_F   (ZCH * YP_P)          // 288
#define YP_OFF (5 * ZP_F)            // 2400
#define LDS_N  (YP_OFF + 5 * YP_F)   // 3840 floats = 15.36 KB

#define NBLK   (NZT * 24 * NCHX * 2) // 2016

#define AI __attribute__((always_inline))

// Drain-free barrier: order LDS (lgkm) only; leave global loads in flight.
// "memory" clobber pins LDS ops on the correct side of the barrier.
#define BAR()                                                    \
    do {                                                         \
        asm volatile("s_waitcnt lgkmcnt(0)" ::: "memory");       \
        __builtin_amdgcn_s_barrier();                            \
        asm volatile("" ::: "memory");                           \
    } while (0)

__global__ __launch_bounds__(256, 4)
void ssim3d_kernel(const float* __restrict__ X, const float* __restrict__ Y,
                   double* __restrict__ acc_out, unsigned* __restrict__ cnt,
                   float* __restrict__ out) {
    __shared__ float lds[LDS_N];
    __shared__ float wsum[4];
    const int tid = threadIdx.x;

    // 1D Gaussian softmax weights, wave-uniform (SGPR).
    float w[7];
    {
        float s = 0.f;
        #pragma unroll
        for (int t = 0; t < 7; ++t) {
            float d = (float)t - 3.0f;
            w[t] = expf(-d * d / 4.5f);
            s += w[t];
        }
        #pragma unroll
        for (int t = 0; t < 7; ++t)
            w[t] = __uint_as_float(__builtin_amdgcn_readfirstlane(__float_as_uint(w[t] / s)));
    }

    // ---- XCD-chunked bijective swizzle ----
    const int L  = blockIdx.x + NZT * (blockIdx.y + 24 * blockIdx.z);
    const int v  = (L & 7) * (NBLK / 8) + (L >> 3);
    const int cb = v / 144;            // combined (cx, n), 0..13
    const int rem = v - cb * 144;
    const int by  = rem % 24;
    const int bz  = rem / 24;          // 0..5
    const int cx  = cb % NCHX;
    const int n   = cb / NCHX;

    const int z0 = bz * ZCH;
    const int y0 = by * YT;
    const int x0 = cx * XCH;

    const float* Xb = X + (size_t)n * VOL;
    const float* Yb = Y + (size_t)n * VOL;

    // z-phase mapping: thread (zj, zs) -> row zj, z-outputs k = zs*2, zs*2+1
    const int zj = tid >> 4;                 // 0..15 (active < 14)
    const int zs = tid & 15;
    const bool zact = (zj < YIN);
    const int zc = z0 + zs * 2;              // first z-input needed
    const int gy = min(y0 + zj, DIMS - 1);
    const unsigned rowoff = (unsigned)gy * DIMS + (unsigned)zc;
    const bool ztail = (zc + 7 > DIMS - 1);  // only last z-tile, zs >= 13

    // y-phase mapping: 160 tasks (5 fields x 32 k), one per thread tid<160
    const int bfld = tid >> 5;               // 0..7 (active < 5)
    const int bk   = tid & 31;
    const bool bact = (bfld < 5);

    // accum mapping: thread owns point (aj, ak); 8 x 32 = 256 exact
    const int aj = tid >> 5;
    const int ak = tid & 31;
    const bool av = (z0 + ak < OD) && (y0 + aj < OD);
    const int xmax = OD + 6 - x0;            // xi < xmax -> output o = x0+xi-6 valid

    float acc[7][5];
    #pragma unroll
    for (int q = 0; q < 7; ++q)
        #pragma unroll
        for (int m = 0; m < 5; ++m) acc[q][m] = 0.f;

    float lsum = 0.f;
    const float c1 = 1e-4f, c2 = 9e-4f;

    float pfx[8], pfy[8];

    auto loadX = [&](int xi) AI {
        if (!zact) return;
        int gx = min(x0 + xi, DIMS - 1);
        const float* p = Xb + (size_t)gx * (DIMS * DIMS);
        if (!ztail) {
            const float* q = p + rowoff;
            #pragma unroll
            for (int t = 0; t < 4; ++t) {
                float2 a = *(const float2*)(q + 2 * t);
                pfx[2 * t] = a.x; pfx[2 * t + 1] = a.y;
            }
        } else {
            unsigned ro = (unsigned)gy * DIMS;
            #pragma unroll
            for (int j = 0; j < 8; ++j)
                pfx[j] = p[ro + (unsigned)min(zc + j, DIMS - 1)];
        }
    };
    auto loadY = [&](int xi) AI {
        if (!zact) return;
        int gx = min(x0 + xi, DIMS - 1);
        const float* p = Yb + (size_t)gx * (DIMS * DIMS);
        if (!ztail) {
            const float* q = p + rowoff;
            #pragma unroll
            for (int t = 0; t < 4; ++t) {
                float2 a = *(const float2*)(q + 2 * t);
                pfy[2 * t] = a.x; pfy[2 * t + 1] = a.y;
            }
        } else {
            unsigned ro = (unsigned)gy * DIMS;
            #pragma unroll
            for (int j = 0; j < 8; ++j)
                pfy[j] = p[ro + (unsigned)min(zc + j, DIMS - 1)];
        }
    };

    auto ssim_pt = [&](float mu1, float mu2, float ex2, float ey2, float exy) AI {
        float mu11 = mu1 * mu1, mu22 = mu2 * mu2, mu12 = mu1 * mu2;
        float num = (2.f * mu12 + c1) * (2.f * (exy - mu12) + c2);
        float den = (mu11 + mu22 + c1) * ((ex2 - mu11) + (ey2 - mu22) + c2);
        lsum += num * __builtin_amdgcn_rcpf(den);
    };

    auto body = [&](int xi, auto ucell) AI {
        constexpr int U = decltype(ucell)::value;   // U == xi % 7

        // ---- Phase A: z-conv from registers -> zp ----
        if (zact) {
            #pragma unroll
            for (int o = 0; o < 2; ++o) {
                float a0 = 0.f, a1 = 0.f, a2 = 0.f, a3 = 0.f, a4 = 0.f;
                #pragma unroll
                for (int t = 0; t < 7; ++t) {
                    float xx = pfx[o + t], yy = pfy[o + t], wt = w[t];
                    a0 += wt * xx;
                    a1 += wt * yy;
                    a2 += wt * (xx * xx);
                    a3 += wt * (yy * yy);
                    a4 += wt * (xx * yy);
                }
                int b = (zs * 2 + o) * ZP_P + zj;
                lds[b]            = a0;
                lds[b + ZP_F]     = a1;
                lds[b + 2 * ZP_F] = a2;
                lds[b + 3 * ZP_F] = a3;
                lds[b + 4 * ZP_F] = a4;
            }
        }
        if (xi + 1 < NP) loadX(xi + 1);   // prefetch X (stays in flight past BAR)
        BAR();

        // ---- Phase B: y-conv zp -> yp (one (field,k) task per thread, tid<160) ----
        if (bact) {
            const float* src = &lds[bfld * ZP_F + bk * ZP_P];
            float vy[YIN];
            #pragma unroll
            for (int jj = 0; jj < YIN; ++jj) vy[jj] = src[jj];
            float* dst = &lds[YP_OFF + bfld * YP_F + bk * YP_P];
            #pragma unroll
            for (int j = 0; j < YT; ++j) {
                float a = 0.f;
                #pragma unroll
                for (int tt = 0; tt < 7; ++tt) a += w[tt] * vy[j + tt];
                dst[j] = a;
            }
        }
        if (xi + 1 < NP) loadY(xi + 1);   // prefetch Y (stays in flight past BAR)
        BAR();

        // ---- Phase C: ring accumulate (compile-time slots) + SSIM ----
        float vv[5];
        #pragma unroll
        for (int f = 0; f < 5; ++f)
            vv[f] = lds[YP_OFF + f * YP_F + ak * YP_P + aj];
        #pragma unroll
        for (int d = 0; d < 7; ++d) {
            float wq = w[d];
            #pragma unroll
            for (int m = 0; m < 5; ++m)
                acc[(U + 7 - d) % 7][m] += wq * vv[m];   // folds to consts after unroll
        }
        constexpr int sc = (U + 1) % 7;   // slot completing at this plane (o = xi-6)
        if (xi >= 6 && xi < xmax && av)
            ssim_pt(acc[sc][0], acc[sc][1], acc[sc][2], acc[sc][3], acc[sc][4]);
        #pragma unroll
        for (int m = 0; m < 5; ++m) acc[sc][m] = 0.f;
        // No 3rd barrier: next Phase A writes zp; this plane's zp reads (Phase B)
        // are behind barrier 2. Phase C's yp reads complete before next Phase B
        // (its writes are behind next barrier 1, whose lgkmcnt(0) covers reads).
    };

    loadX(0); loadY(0);
    #pragma unroll 1
    for (int b = 0; b < 28; b += 7) {
        body(b + 0, std::integral_constant<int, 0>{});
        body(b + 1, std::integral_constant<int, 1>{});
        body(b + 2, std::integral_constant<int, 2>{});
        body(b + 3, std::integral_constant<int, 3>{});
        body(b + 4, std::integral_constant<int, 4>{});
        body(b + 5, std::integral_constant<int, 5>{});
        body(b + 6, std::integral_constant<int, 6>{});
    }
    body(28, std::integral_constant<int, 0>{});
    body(29, std::integral_constant<int, 1>{});
    body(30, std::integral_constant<int, 2>{});
    body(31, std::integral_constant<int, 3>{});
    body(32, std::integral_constant<int, 4>{});

    // ---- block reduction + fused finalize ----
    #pragma unroll
    for (int off = 32; off > 0; off >>= 1) lsum += __shfl_down(lsum, off, 64);
    if ((tid & 63) == 0) wsum[tid >> 6] = lsum;
    __syncthreads();
    if (tid == 0) {
        double bs = (double)(wsum[0] + wsum[1] + wsum[2] + wsum[3]);
        atomicAdd(acc_out, bs);
        __threadfence();
        unsigned prev = atomicAdd(cnt, 1u);
        if (prev == (unsigned)(NBLK - 1)) {
            double tot = atomicAdd(acc_out, 0.0);   // device-scope read of final sum
            out[0] = (float)(tot / 12869712.0);     // 2 * 186^3
        }
    }
}

extern "C" void kernel_launch(void* const* d_in, const int* in_sizes, int n_in,
                              void* d_out, int out_size, void* d_ws, size_t ws_size,
                              hipStream_t stream) {
    (void)in_sizes; (void)n_in; (void)out_size; (void)ws_size;
    const float* x = (const float*)d_in[0];
    const float* y = (const float*)d_in[1];
    double* acc = (double*)d_ws;
    unsigned* cnt = (unsigned*)((char*)d_ws + 8);
    hipMemsetAsync(d_ws, 0, 16, stream);
    dim3 grid(NZT, 24, NCHX * 2);   // z-tiles, y-tiles, x-chunks*batch
    ssim3d_kernel<<<grid, 256, 0, stream>>>(x, y, acc, cnt, (float*)d_out);
}

// Round 7
// 243.736 us; speedup vs baseline: 1.4256x; 1.2172x over previous
//
#include <hip/hip_runtime.h>
#include <utility>

// SSIM3D fused v11: v4 geometry (the proven winner) minus its spill.
//  - Rounds 1-6 evidence: small blocks (ZCH=32, 2016 blocks) never beat v4's
//    142 us even spill-free (v8 202 us) -- occupancy stayed ~35% and per-block
//    fixed costs (66 barrier convoys + load-latency exposures) doubled.
//    Drain-free barriers: no effect (v10). => fewer, larger blocks win.
//  - v4's only defect: spill cascade at cap 128 (pressure ~130) -> VGPR 64 +
//    140 MB scratch. v11: launch_bounds(256,3) -> cap 170 >> pressure ~130
//    (v8 proved headroom prevents the cascade). Occupancy unchanged (~3
//    blocks/CU); scratch round-trips and their reload latencies gone.
//  - Carried from v8: XCD-chunked bijective swizzle (1008 = 8x126), fused
//    last-block finalize. Plain __syncthreads (v10 raw-barrier was neutral).

#define DIMS 192
#define OD   186
#define VOL  (DIMS * DIMS * DIMS)
#define ZCH  62      // z outputs per block (3*62 = 186)
#define NZT  3
#define XCH  27      // x outputs per chunk (7*27 = 189 >= 186, last chunk clipped)
#define NCHX 7
#define NP   (XCH + 6)   // 33 input planes
#define YT   8
#define YIN  14

// LDS layouts (floats):
//  zp[f][k][j]: f*930 + k*15 + j   (pitch 15: z-writes & y-reads <=2-way free)
//  yp[f][k][j]: f*576 + k*9  + j   (pitch 9: all accesses <=2-way free; k padded to 64)
#define ZP_P   15
#define ZP_F   (ZCH * ZP_P)          // 930
#define YP_F   576                   // 64*9
#define YP_OFF (5 * ZP_F)            // 4650
#define LDS_N  (YP_OFF + 5 * YP_F)   // 7530 floats = 30.1 KB

#define NBLK   (NZT * 24 * NCHX * 2) // 1008

#define AI __attribute__((always_inline))

__global__ __launch_bounds__(256, 3)
void ssim3d_kernel(const float* __restrict__ X, const float* __restrict__ Y,
                   double* __restrict__ acc_out, unsigned* __restrict__ cnt,
                   float* __restrict__ out) {
    __shared__ float lds[LDS_N];
    __shared__ float wsum[4];
    const int tid = threadIdx.x;

    // 1D Gaussian softmax weights, wave-uniform (SGPR).
    float w[7];
    {
        float s = 0.f;
        #pragma unroll
        for (int t = 0; t < 7; ++t) {
            float d = (float)t - 3.0f;
            w[t] = expf(-d * d / 4.5f);
            s += w[t];
        }
        #pragma unroll
        for (int t = 0; t < 7; ++t)
            w[t] = __uint_as_float(__builtin_amdgcn_readfirstlane(__float_as_uint(w[t] / s)));
    }

    // ---- XCD-chunked bijective swizzle (1008 = 8 x 126 exact) ----
    // Each XCD gets a contiguous chunk of 126 blocks ordered y-fastest so
    // co-resident blocks on one XCD share plane rows in its L2.
    const int L  = blockIdx.x + NZT * (blockIdx.y + 24 * blockIdx.z);
    const int v  = (L & 7) * (NBLK / 8) + (L >> 3);
    const int cb = v / 72;             // combined (cx, n), 0..13
    const int rem = v - cb * 72;
    const int by  = rem % 24;
    const int bz  = rem / 24;          // 0..2
    const int cx  = cb % NCHX;
    const int n   = cb / NCHX;

    const int z0 = bz * ZCH;
    const int y0 = by * YT;
    const int x0 = cx * XCH;

    const float* Xb = X + (size_t)n * VOL;
    const float* Yb = Y + (size_t)n * VOL;

    // z-phase mapping: thread (zj, zs) -> row zj, z-cols zc..zc+9 (4 outputs)
    const int zj = tid >> 4;                 // 0..15 (active < 14)
    const int zs = tid & 15;
    const bool zact = (zj < YIN);
    const int zc = z0 + zs * 4;
    const int gy = min(y0 + zj, DIMS - 1);
    const unsigned rowoff = (unsigned)gy * DIMS + (unsigned)zc;
    const bool ztail = (zc + 9 > DIMS - 1);  // only z0=124, zs=15

    // y-phase mapping: 310 tasks split evenly across 4 waves (77/78 each)
    const int wv = tid >> 6;
    const int ln = tid & 63;
    const int ybase = (310 * wv) >> 2;
    const int ycnt  = ((310 * (wv + 1)) >> 2) - ybase;

    // accum mapping: thread owns points (aj, ak) and (aj+4, ak)
    const int aj = wv;
    const int ak = ln;
    const bool v1 = (ak < ZCH) && (y0 + aj < OD);
    const bool v2 = (ak < ZCH) && (y0 + aj + 4 < OD);
    const int xmax = OD + 6 - x0;            // xi < xmax -> output o = x0+xi-6 valid

    float acc[7][10];
    #pragma unroll
    for (int q = 0; q < 7; ++q)
        #pragma unroll
        for (int m = 0; m < 10; ++m) acc[q][m] = 0.f;

    float lsum = 0.f;
    const float c1 = 1e-4f, c2 = 9e-4f;

    float pfx[10], pfy[10];

    auto loadX = [&](int xi) AI {
        if (!zact) return;
        int gx = min(x0 + xi, DIMS - 1);
        const float* p = Xb + (size_t)gx * (DIMS * DIMS) + rowoff;
        #pragma unroll
        for (int t = 0; t < 4; ++t) {
            float2 a = *(const float2*)(p + 2 * t);
            pfx[2 * t] = a.x; pfx[2 * t + 1] = a.y;
        }
        if (!ztail) {
            float2 a = *(const float2*)(p + 8);
            pfx[8] = a.x; pfx[9] = a.y;
        } else { pfx[8] = 0.f; pfx[9] = 0.f; }
    };
    auto loadY = [&](int xi) AI {
        if (!zact) return;
        int gx = min(x0 + xi, DIMS - 1);
        const float* p = Yb + (size_t)gx * (DIMS * DIMS) + rowoff;
        #pragma unroll
        for (int t = 0; t < 4; ++t) {
            float2 a = *(const float2*)(p + 2 * t);
            pfy[2 * t] = a.x; pfy[2 * t + 1] = a.y;
        }
        if (!ztail) {
            float2 a = *(const float2*)(p + 8);
            pfy[8] = a.x; pfy[9] = a.y;
        } else { pfy[8] = 0.f; pfy[9] = 0.f; }
    };

    auto ssim_pt = [&](float mu1, float mu2, float ex2, float ey2, float exy) AI {
        float mu11 = mu1 * mu1, mu22 = mu2 * mu2, mu12 = mu1 * mu2;
        float num = (2.f * mu12 + c1) * (2.f * (exy - mu12) + c2);
        float den = (mu11 + mu22 + c1) * ((ex2 - mu11) + (ey2 - mu22) + c2);
        lsum += num * __builtin_amdgcn_rcpf(den);
    };

    auto body = [&](int xi, auto ucell) AI {
        constexpr int U = decltype(ucell)::value;   // U == xi % 7

        // ---- Phase A: z-conv from registers -> zp ----
        if (zact) {
            #pragma unroll
            for (int o = 0; o < 4; ++o) {
                float a0 = 0.f, a1 = 0.f, a2 = 0.f, a3 = 0.f, a4 = 0.f;
                #pragma unroll
                for (int t = 0; t < 7; ++t) {
                    float xx = pfx[o + t], yy = pfy[o + t], wt = w[t];
                    a0 += wt * xx;
                    a1 += wt * yy;
                    a2 += wt * (xx * xx);
                    a3 += wt * (yy * yy);
                    a4 += wt * (xx * yy);
                }
                int k = zs * 4 + o;
                if (k < ZCH) {
                    int b = k * ZP_P + zj;
                    lds[b]            = a0;
                    lds[b + ZP_F]     = a1;
                    lds[b + 2 * ZP_F] = a2;
                    lds[b + 3 * ZP_F] = a3;
                    lds[b + 4 * ZP_F] = a4;
                }
            }
        }
        if (xi + 1 < NP) loadX(xi + 1);   // prefetch X-field (WAR-safe, in-order issue)
        __syncthreads();

        // ---- Phase B: y-conv zp -> yp (balanced across waves) ----
        #pragma unroll
        for (int p2 = 0; p2 < 2; ++p2) {
            int rel = p2 * 64 + ln;
            if (rel < ycnt) {
                int t = ybase + rel;
                int f = t / ZCH;
                int k = t - f * ZCH;
                const float* src = &lds[f * ZP_F + k * ZP_P];
                float vy[YIN];
                #pragma unroll
                for (int jj = 0; jj < YIN; ++jj) vy[jj] = src[jj];
                float* dst = &lds[YP_OFF + f * YP_F + k * 9];
                #pragma unroll
                for (int j = 0; j < YT; ++j) {
                    float a = 0.f;
                    #pragma unroll
                    for (int tt = 0; tt < 7; ++tt) a += w[tt] * vy[j + tt];
                    dst[j] = a;
                }
            }
        }
        if (xi + 1 < NP) loadY(xi + 1);   // prefetch Y-field
        __syncthreads();

        // ---- Phase C: ring accumulate (compile-time slots) + SSIM ----
        float vv[10];
        #pragma unroll
        for (int f = 0; f < 5; ++f) {
            vv[2 * f]     = lds[YP_OFF + f * YP_F + ak * 9 + aj];
            vv[2 * f + 1] = lds[YP_OFF + f * YP_F + ak * 9 + aj + 4];
        }
        #pragma unroll
        for (int d = 0; d < 7; ++d) {
            float wq = w[d];
            #pragma unroll
            for (int m = 0; m < 10; ++m)
                acc[(U + 7 - d) % 7][m] += wq * vv[m];   // folds to consts after unroll
        }
        constexpr int sc = (U + 1) % 7;   // slot completing at this plane (o = xi-6)
        if (xi >= 6 && xi < xmax) {
            if (v1) ssim_pt(acc[sc][0], acc[sc][2], acc[sc][4], acc[sc][6], acc[sc][8]);
            if (v2) ssim_pt(acc[sc][1], acc[sc][3], acc[sc][5], acc[sc][7], acc[sc][9]);
        }
        #pragma unroll
        for (int m = 0; m < 10; ++m) acc[sc][m] = 0.f;
        // No 3rd barrier: next Phase A writes zp; this plane's zp reads (Phase B)
        // are behind barrier 2. Phase C's yp reads complete before next Phase B
        // (its writes are behind next barrier 1).
    };

    loadX(0); loadY(0);
    #pragma unroll 1
    for (int b = 0; b < 28; b += 7) {
        body(b + 0, std::integral_constant<int, 0>{});
        body(b + 1, std::integral_constant<int, 1>{});
        body(b + 2, std::integral_constant<int, 2>{});
        body(b + 3, std::integral_constant<int, 3>{});
        body(b + 4, std::integral_constant<int, 4>{});
        body(b + 5, std::integral_constant<int, 5>{});
        body(b + 6, std::integral_constant<int, 6>{});
    }
    body(28, std::integral_constant<int, 0>{});
    body(29, std::integral_constant<int, 1>{});
    body(30, std::integral_constant<int, 2>{});
    body(31, std::integral_constant<int, 3>{});
    body(32, std::integral_constant<int, 4>{});

    // ---- block reduction + fused finalize ----
    #pragma unroll
    for (int off = 32; off > 0; off >>= 1) lsum += __shfl_down(lsum, off, 64);
    if ((tid & 63) == 0) wsum[tid >> 6] = lsum;
    __syncthreads();
    if (tid == 0) {
        double bs = (double)(wsum[0] + wsum[1] + wsum[2] + wsum[3]);
        atomicAdd(acc_out, bs);
        __threadfence();
        unsigned prev = atomicAdd(cnt, 1u);
        if (prev == (unsigned)(NBLK - 1)) {
            double tot = atomicAdd(acc_out, 0.0);   // device-scope read of final sum
            out[0] = (float)(tot / 12869712.0);     // 2 * 186^3
        }
    }
}

extern "C" void kernel_launch(void* const* d_in, const int* in_sizes, int n_in,
                              void* d_out, int out_size, void* d_ws, size_t ws_size,
                              hipStream_t stream) {
    (void)in_sizes; (void)n_in; (void)out_size; (void)ws_size;
    const float* x = (const float*)d_in[0];
    const float* y = (const float*)d_in[1];
    double* acc = (double*)d_ws;
    unsigned* cnt = (unsigned*)((char*)d_ws + 8);
    hipMemsetAsync(d_ws, 0, 16, stream);
    dim3 grid(NZT, 24, NCHX * 2);   // z-tiles, y-tiles, x-chunks*batch
    ssim3d_kernel<<<grid, 256, 0, stream>>>(x, y, acc, cnt, (float*)d_out);
}